// Round 6
// baseline (193.055 us; speedup 1.0000x reference)
//
#include <hip/hip_runtime.h>
#include <math.h>

// SCNCore: hidden = sigmoid((concept@Wci^T)*(x@Win^T) + (concept@Wcs^T)*(h@Wst^T))
//          i,f,o,cc = split(hidden,4); c_t = i*cc + f*c_state; h_t = o*tanh(c_t)
// B=1024, IN=H=1024, C=1000, 4H=4096. Inputs fp32, outputs fp32.
//
// R6: GEMM was LDS-BW-bound (2.1 GB LDS traffic ~ 84% of ds_read ceiling).
//  (1) A-operand direct-to-registers (global 16B/lane, same frag mapping) --
//      kills A's LDS write + af LDS read (2.1 -> ~1.3 GB).
//  (2) Gate-interleaved N-tiles: block covers cols {c,c+1024,c+2048,c+3072}
//      (ni = gate) => LSTM combine fused into epilogue; no hidden buffer.
//  (3) One convert kernel (weights+activations fp32->bf16, K 1000->1024 pad).

typedef __bf16 bf16_t;
typedef __bf16 bf16x8 __attribute__((ext_vector_type(8)));
typedef float floatx4 __attribute__((ext_vector_type(4)));

#define THREADS 256
#define H4 4096

__device__ __forceinline__ void glds16(const void* g, void* l) {
  __builtin_amdgcn_global_load_lds((const __attribute__((address_space(1))) void*)g,
                                   (__attribute__((address_space(3))) void*)l,
                                   16, 0, 0);
}

// ============================ convert (single launch) ============================
__global__ __launch_bounds__(THREADS)
void conv_all(const float* __restrict__ x, const float* __restrict__ h,
              const float* __restrict__ Win, const float* __restrict__ Wst,
              const float* __restrict__ cpt, const float* __restrict__ Wci,
              const float* __restrict__ Wcs,
              bf16_t* __restrict__ xb, bf16_t* __restrict__ hb,
              bf16_t* __restrict__ Winb, bf16_t* __restrict__ Wstb,
              bf16_t* __restrict__ cb, bf16_t* __restrict__ Wcib,
              bf16_t* __restrict__ Wcsb)
{
  const int bid = blockIdx.x;
  if (bid < 5120) {
    // unpadded: x(131072 ch), h(131072), Win(524288), Wst(524288) -- 8-elem chunks
    const int c = bid * THREADS + threadIdx.x;
    const float* src; bf16_t* dst; int off;
    if      (c < 131072) { src = x;   dst = xb;   off = c; }
    else if (c < 262144) { src = h;   dst = hb;   off = c - 131072; }
    else if (c < 786432) { src = Win; dst = Winb; off = c - 262144; }
    else                 { src = Wst; dst = Wstb; off = c - 786432; }
    const size_t e0 = (size_t)off * 8;
    const float4 f0 = *(const float4*)(src + e0);
    const float4 f1 = *(const float4*)(src + e0 + 4);
    bf16x8 v;
    v[0] = (bf16_t)f0.x; v[1] = (bf16_t)f0.y; v[2] = (bf16_t)f0.z; v[3] = (bf16_t)f0.w;
    v[4] = (bf16_t)f1.x; v[5] = (bf16_t)f1.y; v[6] = (bf16_t)f1.z; v[7] = (bf16_t)f1.w;
    *(bf16x8*)(dst + e0) = v;
  } else {
    // padded K 1000->1024: concept(1024 rows), Wci(4096), Wcs(4096); 2 rows/block
    const int rid   = (bid - 5120) * 2 + (threadIdx.x >> 7);
    const int chunk = threadIdx.x & 127;
    const float* src; bf16_t* dst; int row;
    if      (rid < 1024) { src = cpt; dst = cb;   row = rid; }
    else if (rid < 5120) { src = Wci; dst = Wcib; row = rid - 1024; }
    else                 { src = Wcs; dst = Wcsb; row = rid - 5120; }
    bf16x8 v;
#pragma unroll
    for (int e = 0; e < 8; ++e) v[e] = (bf16_t)0.f;
    if (chunk < 125) {
      const size_t s0 = (size_t)row * 1000 + (size_t)chunk * 8;
      const float4 f0 = *(const float4*)(src + s0);
      const float4 f1 = *(const float4*)(src + s0 + 4);
      v[0] = (bf16_t)f0.x; v[1] = (bf16_t)f0.y; v[2] = (bf16_t)f0.z; v[3] = (bf16_t)f0.w;
      v[4] = (bf16_t)f1.x; v[5] = (bf16_t)f1.y; v[6] = (bf16_t)f1.z; v[7] = (bf16_t)f1.w;
    }
    *(bf16x8*)(dst + (size_t)row * 1024 + (size_t)chunk * 8) = v;
  }
}

// ===================== fused GEMM + LSTM epilogue =====================
// Stage a 64-row x 128 B W-tile, gate-interleaved rows:
// tile row r (0..63) holds W row N0 + (r&15) + (r>>4)*1024. XOR-swizzled chunks.
__device__ __forceinline__ void stageW(const bf16_t* __restrict__ Wb, int N0, int kByte,
                                       char* s, int w, int lane) {
#pragma unroll
  for (int it = 0; it < 2; ++it) {
    const int flat = it * 4096 + w * 1024 + lane * 16;
    const int row  = flat >> 7;
    const int slot = (flat >> 4) & 7;
    const int srcb = kByte + ((slot ^ (row & 7)) << 4);
    const int wrow = N0 + (row & 15) + ((row >> 4) << 10);
    glds16((const char*)Wb + (size_t)wrow * 2048 + srcb, s + it * 4096 + w * 1024);
  }
}

// A-frag direct load: A[m = rowBase + l15][k = kb64 + ks*32 + quad*8], 16 B.
__device__ __forceinline__ bf16x8 loadA(const bf16_t* __restrict__ A, int rowBase,
                                        int l15, int quad, int kByteBase) {
  return *(const bf16x8*)((const char*)A + (size_t)(rowBase + l15) * 2048
                          + kByteBase + quad * 16);
}

__global__ __launch_bounds__(THREADS)
void scn_fused(const bf16_t* __restrict__ xb,   const bf16_t* __restrict__ hb,
               const bf16_t* __restrict__ cb,
               const bf16_t* __restrict__ Winb, const bf16_t* __restrict__ Wstb,
               const bf16_t* __restrict__ Wcib, const bf16_t* __restrict__ Wcsb,
               const float* __restrict__ cs, float* __restrict__ out)
{
  __shared__ __align__(16) char sB1[64 * 128];  // 8 KiB
  __shared__ __align__(16) char sB2[64 * 128];  // 8 KiB
  const int tid = threadIdx.x;
  const int w = tid >> 6, lane = tid & 63, l15 = lane & 15, quad = lane >> 4;
  const int N0 = blockIdx.x * 16;    // 16 cols per gate; grid.x = 64
  const int M0 = blockIdx.y * 128;   // grid.y = 8
  const int rowBase = M0 + w * 32;   // wave handles rows rowBase..rowBase+31

  floatx4 a_xi[2][4], a_hs[2][4], a_gi[2][4], a_gs[2][4];
  const floatx4 z = {0.f, 0.f, 0.f, 0.f};
#pragma unroll
  for (int mi = 0; mi < 2; ++mi)
#pragma unroll
    for (int ni = 0; ni < 4; ++ni) {
      a_xi[mi][ni] = z; a_hs[mi][ni] = z; a_gi[mi][ni] = z; a_gs[mi][ni] = z;
    }

  // ---- phase 1: concept vs (Wci, Wcs) -> gi, gs ----
  for (int i = 0; i < 16; ++i) {
    const int kb = i * 128;
    __syncthreads();
    stageW(Wcib, N0, kb, sB1, w, lane);
    stageW(Wcsb, N0, kb, sB2, w, lane);
    __syncthreads();
#pragma unroll
    for (int ks = 0; ks < 2; ++ks) {
      bf16x8 af[2], b1[4], b2[4];
#pragma unroll
      for (int mi = 0; mi < 2; ++mi)
        af[mi] = loadA(cb, rowBase + mi * 16, l15, quad, kb + ks * 64);
#pragma unroll
      for (int ni = 0; ni < 4; ++ni) {
        const int r = ni * 16 + l15;
        const int c = (ks * 4 + quad) ^ (r & 7);
        b1[ni] = *(const bf16x8*)(sB1 + r * 128 + c * 16);
        b2[ni] = *(const bf16x8*)(sB2 + r * 128 + c * 16);
      }
#pragma unroll
      for (int mi = 0; mi < 2; ++mi)
#pragma unroll
        for (int ni = 0; ni < 4; ++ni) {
          a_gi[mi][ni] = __builtin_amdgcn_mfma_f32_16x16x32_bf16(af[mi], b1[ni], a_gi[mi][ni], 0, 0, 0);
          a_gs[mi][ni] = __builtin_amdgcn_mfma_f32_16x16x32_bf16(af[mi], b2[ni], a_gs[mi][ni], 0, 0, 0);
        }
    }
  }

  // ---- phase 2: x vs Win -> xi ; h vs Wst -> hs ----
  for (int i = 0; i < 16; ++i) {
    const int kb = i * 128;
    __syncthreads();
    stageW(Winb, N0, kb, sB1, w, lane);
    stageW(Wstb, N0, kb, sB2, w, lane);
    __syncthreads();
#pragma unroll
    for (int ks = 0; ks < 2; ++ks) {
      bf16x8 ax[2], ah[2], b1[4], b2[4];
#pragma unroll
      for (int mi = 0; mi < 2; ++mi) {
        ax[mi] = loadA(xb, rowBase + mi * 16, l15, quad, kb + ks * 64);
        ah[mi] = loadA(hb, rowBase + mi * 16, l15, quad, kb + ks * 64);
      }
#pragma unroll
      for (int ni = 0; ni < 4; ++ni) {
        const int r = ni * 16 + l15;
        const int c = (ks * 4 + quad) ^ (r & 7);
        b1[ni] = *(const bf16x8*)(sB1 + r * 128 + c * 16);
        b2[ni] = *(const bf16x8*)(sB2 + r * 128 + c * 16);
      }
#pragma unroll
      for (int mi = 0; mi < 2; ++mi)
#pragma unroll
        for (int ni = 0; ni < 4; ++ni) {
          a_xi[mi][ni] = __builtin_amdgcn_mfma_f32_16x16x32_bf16(ax[mi], b1[ni], a_xi[mi][ni], 0, 0, 0);
          a_hs[mi][ni] = __builtin_amdgcn_mfma_f32_16x16x32_bf16(ah[mi], b2[ni], a_hs[mi][ni], 0, 0, 0);
        }
    }
  }

  // ---- epilogue: gates (fp32) -> c_t, h_t; C/D row = quad*4 + r, col = l15 ----
#pragma unroll
  for (int mi = 0; mi < 2; ++mi)
#pragma unroll
    for (int r = 0; r < 4; ++r) {
      float g[4];
#pragma unroll
      for (int ni = 0; ni < 4; ++ni) {
        const float e = a_gi[mi][ni][r] * a_xi[mi][ni][r]
                      + a_gs[mi][ni][r] * a_hs[mi][ni][r];
        g[ni] = 1.f / (1.f + __expf(-e));       // ni: 0=i, 1=f, 2=o, 3=cc
      }
      const int row = rowBase + mi * 16 + quad * 4 + r;
      const int col = N0 + l15;
      const float cst = cs[(size_t)row * 1024 + col];
      const float ct = g[0] * g[3] + g[1] * cst;
      const float ht = g[2] * tanhf(ct);
      out[(size_t)row * 1024 + col]             = ht;
      out[(size_t)(1u << 20) + row * 1024 + col] = ct;
    }
}

// ============================ legacy fallback (R4, known-good) ============================
__device__ __forceinline__ void compute_block_l(const char* sA, const char* sB,
                                                int w, int l15, int quad,
                                                floatx4 (&acc)[2][4]) {
#pragma unroll
  for (int ks = 0; ks < 2; ++ks) {
    bf16x8 af[2], bfr[4];
#pragma unroll
    for (int mi = 0; mi < 2; ++mi) {
      const int r = w * 32 + mi * 16 + l15;
      const int c = (ks * 4 + quad) ^ (r & 7);
      af[mi] = *(const bf16x8*)(sA + r * 128 + c * 16);
    }
#pragma unroll
    for (int ni = 0; ni < 4; ++ni) {
      const int r = ni * 16 + l15;
      const int c = (ks * 4 + quad) ^ (r & 7);
      bfr[ni] = *(const bf16x8*)(sB + r * 128 + c * 16);
    }
#pragma unroll
    for (int mi = 0; mi < 2; ++mi)
#pragma unroll
      for (int ni = 0; ni < 4; ++ni)
        acc[mi][ni] = __builtin_amdgcn_mfma_f32_16x16x32_bf16(af[mi], bfr[ni], acc[mi][ni], 0, 0, 0);
  }
}

template<int ITERS>
__device__ __forceinline__ void stage_tile_f32(const char* __restrict__ g, int row0,
                                               int Kelems, int kBase, char* s, int tid)
{
#pragma unroll
  for (int it = 0; it < ITERS; ++it) {
    const int flat = it * 4096 + tid * 16;
    const int row  = flat >> 7;
    const int slot = (flat >> 4) & 7;
    const int eb   = kBase + ((slot ^ (row & 7)) << 3);
    bf16x8 v;
#pragma unroll
    for (int e = 0; e < 8; ++e) v[e] = (bf16_t)0.f;
    if (eb + 8 <= Kelems) {
      const size_t e0 = (size_t)(row0 + row) * (size_t)Kelems + (size_t)eb;
      const float4 f0 = *(const float4*)(g + e0 * 4);
      const float4 f1 = *(const float4*)(g + e0 * 4 + 16);
      v[0] = (bf16_t)f0.x; v[1] = (bf16_t)f0.y; v[2] = (bf16_t)f0.z; v[3] = (bf16_t)f0.w;
      v[4] = (bf16_t)f1.x; v[5] = (bf16_t)f1.y; v[6] = (bf16_t)f1.z; v[7] = (bf16_t)f1.w;
    }
    *(bf16x8*)(s + flat) = v;
  }
}

__device__ __forceinline__ void gemm_phase_legacy(
    const char* __restrict__ gA, int M0, const char* __restrict__ gW, int N0,
    int Kelems, char* sA, char* sB, int tid, floatx4 (&acc)[2][4])
{
  const int w = tid >> 6, lane = tid & 63, l15 = lane & 15, quad = lane >> 4;
  const int iters = (Kelems + 63) >> 6;
  for (int i = 0; i < iters; ++i) {
    const int kb = i * 64;
    __syncthreads();
    stage_tile_f32<4>(gA, M0, Kelems, kb, sA, tid);
    stage_tile_f32<2>(gW, N0, Kelems, kb, sB, tid);
    __syncthreads();
    compute_block_l(sA, sB, w, l15, quad, acc);
  }
}

__global__ __launch_bounds__(THREADS)
void scn_gemm_legacy(const char* __restrict__ x, const char* __restrict__ h,
                     const char* __restrict__ cpt,
                     const char* __restrict__ Win, const char* __restrict__ Wst,
                     const char* __restrict__ Wci, const char* __restrict__ Wcs,
                     bf16_t* __restrict__ hidden)
{
  __shared__ __align__(16) char sA[128 * 128];
  __shared__ __align__(16) char sB[64 * 128];
  const int tid = threadIdx.x;
  const int N0 = blockIdx.x * 64, M0 = blockIdx.y * 128;
  floatx4 acc0[2][4], acc1[2][4], acc2[2][4];
  const floatx4 z = {0.f, 0.f, 0.f, 0.f};
#pragma unroll
  for (int mi = 0; mi < 2; ++mi)
#pragma unroll
    for (int ni = 0; ni < 4; ++ni) { acc0[mi][ni] = z; acc1[mi][ni] = z; acc2[mi][ni] = z; }
  gemm_phase_legacy(x, M0, Win, N0, 1024, sA, sB, tid, acc0);
  gemm_phase_legacy(cpt, M0, Wci, N0, 1000, sA, sB, tid, acc1);
#pragma unroll
  for (int mi = 0; mi < 2; ++mi)
#pragma unroll
    for (int ni = 0; ni < 4; ++ni) { acc0[mi][ni] = acc0[mi][ni] * acc1[mi][ni]; acc1[mi][ni] = z; }
  gemm_phase_legacy(h, M0, Wst, N0, 1024, sA, sB, tid, acc1);
  gemm_phase_legacy(cpt, M0, Wcs, N0, 1000, sA, sB, tid, acc2);
  const int w = tid >> 6, lane = tid & 63, l15 = lane & 15, quad = lane >> 4;
#pragma unroll
  for (int mi = 0; mi < 2; ++mi)
#pragma unroll
    for (int ni = 0; ni < 4; ++ni)
#pragma unroll
      for (int r = 0; r < 4; ++r) {
        const float e = acc0[mi][ni][r] + acc1[mi][ni][r] * acc2[mi][ni][r];
        const float s = 1.f / (1.f + __expf(-e));
        const int row = M0 + w * 32 + mi * 16 + quad * 4 + r;
        const int col = N0 + ni * 16 + l15;
        hidden[(size_t)row * H4 + col] = (bf16_t)s;
      }
}

__global__ __launch_bounds__(THREADS)
void scn_combine(const bf16_t* __restrict__ hidden, const float* __restrict__ cs,
                 float* __restrict__ out)
{
  const int t = blockIdx.x * THREADS + threadIdx.x;
  const size_t idx = (size_t)t * 8;
  const size_t b = idx >> 10, col = idx & 1023;
  const size_t hb = b * H4 + col;
  const bf16x8 vi = *(const bf16x8*)(hidden + hb);
  const bf16x8 vf = *(const bf16x8*)(hidden + hb + 1024);
  const bf16x8 vo = *(const bf16x8*)(hidden + hb + 2048);
  const bf16x8 vc = *(const bf16x8*)(hidden + hb + 3072);
  const float4 a = *(const float4*)(cs + idx);
  const float4 d = *(const float4*)(cs + idx + 4);
  const float cv[8] = {a.x, a.y, a.z, a.w, d.x, d.y, d.z, d.w};
  float ht[8], ct[8];
#pragma unroll
  for (int e = 0; e < 8; ++e) {
    ct[e] = (float)vi[e] * (float)vc[e] + (float)vf[e] * cv[e];
    ht[e] = (float)vo[e] * tanhf(ct[e]);
  }
  *(float4*)(out + idx)     = make_float4(ht[0], ht[1], ht[2], ht[3]);
  *(float4*)(out + idx + 4) = make_float4(ht[4], ht[5], ht[6], ht[7]);
  float* outc = out + (1u << 20);
  *(float4*)(outc + idx)     = make_float4(ct[0], ct[1], ct[2], ct[3]);
  *(float4*)(outc + idx + 4) = make_float4(ct[4], ct[5], ct[6], ct[7]);
}

extern "C" void kernel_launch(void* const* d_in, const int* in_sizes, int n_in,
                              void* d_out, int out_size, void* d_ws, size_t ws_size,
                              hipStream_t stream) {
  (void)in_sizes; (void)n_in; (void)out_size;
  const float* x   = (const float*)d_in[0];
  const float* h   = (const float*)d_in[1];
  const float* cst = (const float*)d_in[2];
  const float* cpt = (const float*)d_in[3];
  const float* Win = (const float*)d_in[4];
  const float* Wst = (const float*)d_in[5];
  const float* Wci = (const float*)d_in[6];
  const float* Wcs = (const float*)d_in[7];
  float* out = (float*)d_out;
  const size_t MB = 1u << 20;

  if (ws_size >= 38 * MB) {
    char* ws = (char*)d_ws;
    bf16_t* xb   = (bf16_t*)(ws);            // 2 MiB
    bf16_t* hbuf = (bf16_t*)(ws + 2 * MB);   // 2 MiB
    bf16_t* cb   = (bf16_t*)(ws + 4 * MB);   // 2 MiB (K padded)
    bf16_t* Winb = (bf16_t*)(ws + 6 * MB);   // 8 MiB
    bf16_t* Wstb = (bf16_t*)(ws + 14 * MB);  // 8 MiB
    bf16_t* Wcib = (bf16_t*)(ws + 22 * MB);  // 8 MiB (K padded)
    bf16_t* Wcsb = (bf16_t*)(ws + 30 * MB);  // 8 MiB (K padded)
    conv_all<<<5120 + 4608, THREADS, 0, stream>>>(x, h, Win, Wst, cpt, Wci, Wcs,
                                                  xb, hbuf, Winb, Wstb, cb, Wcib, Wcsb);
    dim3 grid(64, 8);   // 512 blocks: 64 gate-col groups x 8 row tiles
    scn_fused<<<grid, THREADS, 0, stream>>>(xb, hbuf, cb, Winb, Wstb, Wcib, Wcsb, cst, out);
  } else {
    bf16_t* hidden = (bf16_t*)((char*)d_ws + 256);
    dim3 grid(H4 / 64, 1024 / 128);
    scn_gemm_legacy<<<grid, THREADS, 0, stream>>>(
        (const char*)x, (const char*)h, (const char*)cpt,
        (const char*)Win, (const char*)Wst, (const char*)Wci, (const char*)Wcs, hidden);
    scn_combine<<<(1024 * 1024 / 8) / THREADS, THREADS, 0, stream>>>(hidden, cst, out);
  }
}